// Round 3
// baseline (461.195 us; speedup 1.0000x reference)
//
#include <hip/hip_runtime.h>
#include <hip/hip_bf16.h>

// Shapes fixed by the reference
#define T_TOK 4096
#define I1    512
#define O1    2049
#define K1    4608        // 8*512 spline + 512 silu (= 576 groups, no pad)
#define NG1   576         // K1/8
#define I2    2049
#define O2    512
#define K2    18560       // 8*2049 spline + 2049 silu + 119 pad = 2320 groups
#define NG2   2320        // K2/8
#define N1G   2048        // GEMM1 N (col 2048 handled by GEMV)
#define HPART ((size_t)T_TOK * N1G)   // one H partial, floats

typedef __attribute__((ext_vector_type(8))) short short8;
typedef __attribute__((ext_vector_type(4))) float floatx4;
typedef __attribute__((address_space(3))) void* lds_ptr_t;
typedef const __attribute__((address_space(1))) void* gmem_ptr_t;

__device__ __forceinline__ unsigned short f2bf(float f) {   // RNE (prep kernels)
  union { __hip_bfloat16 h; unsigned short u; } cv;
  cv.h = __float2bfloat16(f);
  return cv.u;
}
__device__ __forceinline__ float b2f(unsigned short u) {
  union { float f; unsigned u; } c; c.u = (unsigned)u << 16; return c.f;
}
__device__ __forceinline__ unsigned bfr(float f) {          // cheap near-RNE (expand hot path)
  union { float f; unsigned u; } c; c.f = f;
  return (c.u + 0x8000u) >> 16;
}
__device__ __forceinline__ float silu_f(float x) { return x / (1.0f + __expf(-x)); }

// All 8 cubic-basis slots for one group as 8 bf16 in a uint4 (branchless funnel shift).
__device__ __forceinline__ uint4 spline_pack(float h) {
  float u = (h + 2.2f) * 2.5f;
  int ji = (int)u;
  ji = ji < 0 ? 0 : (ji > 10 ? 10 : ji);
  float t = u - (float)ji;
  float it = 1.0f - t, t2 = t * t, t3 = t2 * t;
  float b0 = it * it * it * (1.0f / 6.0f);
  float b1 = (3.0f * t3 - 6.0f * t2 + 4.0f) * (1.0f / 6.0f);
  float b2 = (-3.0f * t3 + 3.0f * t2 + 3.0f * t + 1.0f) * (1.0f / 6.0f);
  float b3 = t3 * (1.0f / 6.0f);
  unsigned pk01 = bfr(b0) | (bfr(b1) << 16);
  unsigned pk23 = bfr(b2) | (bfr(b3) << 16);
  unsigned long long p64 = (unsigned long long)pk01 | ((unsigned long long)pk23 << 32);
  bool inR = (h >= -2.2f) && (h < 2.2f);
  p64 = inR ? p64 : 0ull;
  int sh = (ji - 3) * 16;
  int shr = sh < 0 ? -sh : 0;
  int shl = sh < 0 ? 0 : sh;
  __uint128_t v = ((__uint128_t)(p64 >> shr)) << shl;
  union { __uint128_t q; uint4 u4; } cv;
  cv.q = v;
  return cv.u4;
}

// W1'[o,k]: k<4096 -> spline_w1[o,k>>3,k&7]*scaler1[o,k>>3]; else base_w1. o < 2049.
__global__ void pack_w1_kernel(const float* __restrict__ bw, const float* __restrict__ sw,
                               const float* __restrict__ sc, unsigned short* __restrict__ W) {
  int k = blockIdx.x * 256 + threadIdx.x;  // grid exact: 18*256 = 4608
  int o = blockIdx.y;                      // < 2049
  float v;
  if (k < 4096) v = sw[(size_t)o * 4096 + k] * sc[(size_t)o * I1 + (k >> 3)];
  else          v = bw[(size_t)o * I1 + (k - 4096)];
  W[(size_t)o * K1 + k] = f2bf(v);
}

// W2'[o,k]: k<16392 -> spline_w2*scaler2; k<18441 -> base_w2; else 0
__global__ void pack_w2_kernel(const float* __restrict__ bw, const float* __restrict__ sw,
                               const float* __restrict__ sc, unsigned short* __restrict__ W) {
  int k = blockIdx.x * 256 + threadIdx.x;
  if (k >= K2) return;
  int o = blockIdx.y;                      // < 512
  float v = 0.0f;
  if (k < 16392)      v = sw[(size_t)o * 16392 + k] * sc[(size_t)o * I2 + (k >> 3)];
  else if (k < 18441) v = bw[(size_t)o * I2 + (k - 16392)];
  W[(size_t)o * K2 + k] = f2bf(v);
}

// A1[m, g*8..g*8+7]: g<512 -> spline basis of x[m,g]; g>=512 -> silu(x[m, (g-512)*8 + c]).
__global__ void expand1_kernel(const float* __restrict__ x, unsigned short* __restrict__ A) {
  int g = blockIdx.x * 256 + threadIdx.x;
  if (g >= NG1) return;
  int m = blockIdx.y;
  uint4 val;
  if (g < 512) {
    val = spline_pack(x[(size_t)m * I1 + g]);
  } else {
    const float4* xr = (const float4*)(x + (size_t)m * I1 + (size_t)(g - 512) * 8);
    float4 a = xr[0], b = xr[1];
    union { unsigned short s[8]; uint4 v; } pk;
    pk.s[0] = f2bf(silu_f(a.x)); pk.s[1] = f2bf(silu_f(a.y));
    pk.s[2] = f2bf(silu_f(a.z)); pk.s[3] = f2bf(silu_f(a.w));
    pk.s[4] = f2bf(silu_f(b.x)); pk.s[5] = f2bf(silu_f(b.y));
    pk.s[6] = f2bf(silu_f(b.z)); pk.s[7] = f2bf(silu_f(b.w));
    val = pk.v;
  }
  *(uint4*)(A + (size_t)m * K1 + (size_t)g * 8) = val;
}

// GEMV: H[:,2048] = A1 @ W1'[2048,:]^T. One wave per row m; 4608 = 9*64 groups of 8.
__global__ void gemv_col_kernel(const unsigned short* __restrict__ A1,
                                const unsigned short* __restrict__ W1,
                                float* __restrict__ Hcol) {
  int m = blockIdx.x * 4 + (threadIdx.x >> 6);
  int lane = threadIdx.x & 63;
  const unsigned short* a  = A1 + (size_t)m * K1;
  const unsigned short* wr = W1 + (size_t)2048 * K1;
  float s = 0.0f;
#pragma unroll
  for (int c = 0; c < 9; ++c) {
    int off = (c * 64 + lane) * 8;
    short8 av = *(const short8*)(a + off);
    short8 wv = *(const short8*)(wr + off);
#pragma unroll
    for (int j = 0; j < 8; ++j)
      s += b2f((unsigned short)av[j]) * b2f((unsigned short)wv[j]);
  }
#pragma unroll
  for (int d = 32; d >= 1; d >>= 1) s += __shfl_down(s, d);
  if (lane == 0) Hcol[m] = s;
}

// A2 from H = Ha + Hb (split-K partials) with H[:,2048] in Hcol.
__global__ void expand2_kernel(const float* __restrict__ Ha, const float* __restrict__ Hb,
                               const float* __restrict__ Hcol, unsigned short* __restrict__ A) {
  int g = blockIdx.x * 256 + threadIdx.x;
  if (g >= NG2) return;
  int m = blockIdx.y;
  float hc = Hcol[m];
  uint4 val;
  if (g < 2049) {
    float h = (g < N1G) ? Ha[(size_t)m * N1G + g] + Hb[(size_t)m * N1G + g] : hc;
    val = spline_pack(h);
  } else if (g < 2306) {
    int c0 = (g - 2049) * 8;
    union { unsigned short s[8]; uint4 v; } pk;
#pragma unroll
    for (int c = 0; c < 8; ++c) {
      int idx = c0 + c;
      float v = 0.0f;
      if (idx < I2) {
        float h = (idx < N1G) ? Ha[(size_t)m * N1G + idx] + Hb[(size_t)m * N1G + idx] : hc;
        v = silu_f(h);
      }
      pk.s[c] = f2bf(v);
    }
    val = pk.v;
  } else {
    val = make_uint4(0u, 0u, 0u, 0u);
  }
  *(uint4*)(A + (size_t)m * K2 + (size_t)g * 8) = val;
}

// ---- 256x256 ring-4 counted-vmcnt GEMM ----
// C = A(MxK) * B(NxK)^T, bf16, 512 threads = 8 waves (2M x 4N), per-wave 128x64.
// BK=32, 4-slot LDS ring per operand (4 x 16KB x 2 = 128 KiB). Body t stages tile
// t+3 and computes tile t -> prefetch distance 3 tiles (~900+ cy cover). One
// barrier per tile; steady-state wait = s_waitcnt vmcnt(8) (tiles t+2,t+3 in
// flight, 4 loads each) -- NEVER 0 in the main loop (T4); tail uses 4/0.
// WAR safety: stage(t+3) overwrites slot (t-1)&3, whose reads completed before
// body t-1's end barrier (lgkmcnt enforced by MFMA data deps). RAW safety:
// vmcnt(own loads) + barrier => all waves' tile-(t+1) loads landed.
// LDS layout per slot: [128 rows][8 x 16B]: slot j of row r holds tile element
// (row r+128*(jj>>2), colgroup jj&3), jj=j^(r&7) -- 8-way XOR swizzle domain
// despite BK=32. Staging source applies the same formula (both-sides rule).
// Fragment reads: per 16-lane group each bank-slot hit exactly 2x (free).
// Requires ntiles >= 3 (both call sites: 72/76).
__global__ __launch_bounds__(512, 2)
void gemm256_kernel(const unsigned short* __restrict__ Aw, const unsigned short* __restrict__ Bw,
                    float* __restrict__ C, int Ktot, int kStep, int nBx, int nBz,
                    int ldc, size_t pslice, int storeMode)
{
  __shared__ __align__(16) unsigned short As[4][8192];
  __shared__ __align__(16) unsigned short Bs[4][8192];

  // XCD-bijective swizzle for 256 blocks, then (bx, by, bz)
  const int Lb = blockIdx.x;
  const int wgid = (Lb & 7) * 32 + (Lb >> 3);
  const int bx = wgid % nBx;
  const int tq = wgid / nBx;
  const int by = tq & 15;
  const int bz = tq >> 4;

  const int tid = threadIdx.x;
  const int ks = bz * kStep;
  const int ke = (bz == nBz - 1) ? Ktot : ks + kStep;
  const int ntiles = (ke - ks) >> 5;

  const int w = tid >> 6, L = tid & 63, q = L >> 4, ln = L & 15;
  const int wmh = w & 1;         // M half (128 rows)
  const int wnq = w >> 1;        // N quarter (64 cols)

  floatx4 zf = {0.f, 0.f, 0.f, 0.f};
  floatx4 acc[8][4];
#pragma unroll
  for (int f = 0; f < 8; ++f)
#pragma unroll
    for (int n = 0; n < 4; ++n)
      acc[f][n] = zf;

  // Staging: 2 chunks/thread/operand/tile. LDS linear dest e*16B; source address
  // pre-applies the slot swizzle: e=(r,j), jj=j^(r&7), trow=(jj>>2)*128+r, colg=jj&3.
  const unsigned short* gA[2];
  const unsigned short* gB[2];
  int ldsO[2];
#pragma unroll
  for (int l = 0; l < 2; ++l) {
    int e = l * 512 + tid;
    int rr = e >> 3, j = e & 7, jj = j ^ (rr & 7);
    int trow = ((jj >> 2) << 7) + rr, tcg = jj & 3;
    gA[l] = Aw + (size_t)(by * 256 + trow) * Ktot + ks + tcg * 8;
    gB[l] = Bw + (size_t)(bx * 256 + trow) * Ktot + ks + tcg * 8;
    ldsO[l] = e * 8;
  }

  // Prologue: stage tiles 0,1,2 into slots 0,1,2; wait tile 0 (vmcnt(8)), barrier.
#pragma unroll
  for (int tt = 0; tt < 3; ++tt) {
#pragma unroll
    for (int l = 0; l < 2; ++l) {
      __builtin_amdgcn_global_load_lds((gmem_ptr_t)(gA[l] + tt * 32), (lds_ptr_t)&As[tt][ldsO[l]], 16, 0, 0);
      __builtin_amdgcn_global_load_lds((gmem_ptr_t)(gB[l] + tt * 32), (lds_ptr_t)&Bs[tt][ldsO[l]], 16, 0, 0);
    }
  }
#pragma unroll
  for (int l = 0; l < 2; ++l) { gA[l] += 96; gB[l] += 96; }
  asm volatile("s_waitcnt vmcnt(8)" ::: "memory");
  asm volatile("s_barrier" ::: "memory");

  // Loop-invariant fragment offsets (within a slot, shorts).
  int aoff[8], boff[4];
#pragma unroll
  for (int f = 0; f < 8; ++f) {
    int r = f * 16 + ln;
    aoff[f] = r * 64 + (((q + (wmh << 2)) ^ (r & 7)) << 3);
  }
#pragma unroll
  for (int n = 0; n < 4; ++n) {
    int rb = wnq * 64 + n * 16 + ln;
    int r = rb & 127;
    boff[n] = r * 64 + (((q + ((wnq >> 1) << 2)) ^ (r & 7)) << 3);
  }

  for (int t = 0; t < ntiles; ++t) {
    const unsigned short* Asp = As[t & 3];
    const unsigned short* Bsp = Bs[t & 3];
    if (t + 3 < ntiles) {                   // stage tile t+3 (slot freed by body t-1)
      int sn = (t + 3) & 3;
#pragma unroll
      for (int l = 0; l < 2; ++l) {
        __builtin_amdgcn_global_load_lds((gmem_ptr_t)gA[l], (lds_ptr_t)&As[sn][ldsO[l]], 16, 0, 0);
        gA[l] += 32;
        __builtin_amdgcn_global_load_lds((gmem_ptr_t)gB[l], (lds_ptr_t)&Bs[sn][ldsO[l]], 16, 0, 0);
        gB[l] += 32;
      }
    }
    __builtin_amdgcn_sched_barrier(0);      // stages issue before reads/MFMA

    short8 af[8], bf[4];
#pragma unroll
    for (int f = 0; f < 8; ++f) af[f] = *(const short8*)&Asp[aoff[f]];
#pragma unroll
    for (int n = 0; n < 4; ++n) bf[n] = *(const short8*)&Bsp[boff[n]];

    __builtin_amdgcn_s_setprio(1);
#pragma unroll
    for (int f = 0; f < 8; ++f)
#pragma unroll
      for (int n = 0; n < 4; ++n)
        acc[f][n] = __builtin_amdgcn_mfma_f32_16x16x32_bf16(af[f], bf[n], acc[f][n], 0, 0, 0);
    __builtin_amdgcn_s_setprio(0);

    // Counted drain: ensure tile t+1 landed; keep t+2,t+3 in flight.
    if (t + 3 < ntiles)       asm volatile("s_waitcnt vmcnt(8)" ::: "memory");
    else if (t + 3 == ntiles) asm volatile("s_waitcnt vmcnt(4)" ::: "memory");
    else                      asm volatile("s_waitcnt vmcnt(0)" ::: "memory");
    asm volatile("s_barrier" ::: "memory");
  }

  // Epilogue. D layout: col = lane&15 (n), row = q*4+reg (m)  [m89-verified]
  const int gmb = by * 256 + wmh * 128 + q * 4;
  const int gnb = bx * 256 + wnq * 64 + ln;
  if (storeMode == 0) {                     // plain store into split-K partial (layer 1)
    float* Cp = C + (size_t)bz * pslice;
#pragma unroll
    for (int f = 0; f < 8; ++f)
#pragma unroll
      for (int n = 0; n < 4; ++n)
#pragma unroll
        for (int rg = 0; rg < 4; ++rg)
          Cp[(size_t)(gmb + f * 16 + rg) * ldc + (gnb + n * 16)] = acc[f][n][rg];
  } else {                                  // atomic accumulate (layer 2, split-K 8)
#pragma unroll
    for (int f = 0; f < 8; ++f)
#pragma unroll
      for (int n = 0; n < 4; ++n)
#pragma unroll
        for (int rg = 0; rg < 4; ++rg)
          atomicAdd(&C[(size_t)(gmb + f * 16 + rg) * ldc + (gnb + n * 16)], acc[f][n][rg]);
  }
}

extern "C" void kernel_launch(void* const* d_in, const int* in_sizes, int n_in,
                              void* d_out, int out_size, void* d_ws, size_t ws_size,
                              hipStream_t stream) {
  const float* x   = (const float*)d_in[0];
  const float* bw1 = (const float*)d_in[1];
  const float* sw1 = (const float*)d_in[2];
  const float* sc1 = (const float*)d_in[3];
  const float* bw2 = (const float*)d_in[4];
  const float* sw2 = (const float*)d_in[5];
  const float* sc2 = (const float*)d_in[6];
  float* out = (float*)d_out;

  // Workspace: Ha(33.6) | Hb(33.6) | Hcol(64KB) | W2(19.0) | A2(152.0; A1 37.7 + W1 18.9 aliased)
  float* Ha = (float*)d_ws;
  float* Hb = Ha + HPART;
  float* Hcol = Hb + HPART;
  unsigned short* W2 = (unsigned short*)(Hcol + 16384);
  unsigned short* A2 = W2 + (size_t)O2 * K2;
  unsigned short* A1 = A2;                              // alias (first 37.7 MB)
  unsigned short* W1 = A1 + (size_t)T_TOK * K1;         // next 18.9 MB

  hipMemsetAsync(d_out, 0, (size_t)out_size * sizeof(float), stream);

  pack_w1_kernel<<<dim3(K1 / 256, O1), 256, 0, stream>>>(bw1, sw1, sc1, W1);
  pack_w2_kernel<<<dim3((K2 + 255) / 256, O2), 256, 0, stream>>>(bw2, sw2, sc2, W2);
  expand1_kernel<<<dim3((NG1 + 255) / 256, T_TOK), 256, 0, stream>>>(x, A1);

  // H column 2048 via GEMV (keeps the big GEMM at N=2048 exactly -> 256 blocks)
  gemv_col_kernel<<<T_TOK / 4, 256, 0, stream>>>(A1, W1, Hcol);

  // Layer 1: Ha/Hb = A1 @ W1'^T. M=4096, N=2048, K=4608; 16x8 spatial x split-K 2 = 256 blocks.
  gemm256_kernel<<<256, 512, 0, stream>>>(A1, W1, Ha, K1, 2304, 8, 2, N1G, HPART, 0);

  expand2_kernel<<<dim3((NG2 + 255) / 256, T_TOK), 256, 0, stream>>>(Ha, Hb, Hcol, A2);

  // Layer 2: out += A2 @ W2'^T. M=4096, N=512, K=18560; 16x2 spatial x split-K 8 = 256 blocks.
  gemm256_kernel<<<256, 512, 0, stream>>>(A2, W2, out, K2, 2304, 2, 8, O2, 0, 2);
}

// Round 4
// 427.790 us; speedup vs baseline: 1.0781x; 1.0781x over previous
//
#include <hip/hip_runtime.h>
#include <hip/hip_bf16.h>

// Shapes fixed by the reference
#define T_TOK 4096
#define I1    512
#define O1    2049
#define K1    4608        // 8*512 spline + 512 silu (= 576 groups, no pad)
#define NG1   576         // K1/8
#define I2    2049
#define O2    512
#define K2    18560       // 8*2049 spline + 2049 silu + 119 pad = 2320 groups
#define NG2   2320        // K2/8
#define N1G   2048        // GEMM1 N (col 2048 handled by GEMV)
#define HPART ((size_t)T_TOK * N1G)   // one H partial, floats
#define SPLITS2 8
#define KLEN2 2368        // 37*64; last slice clamps to 31 iters
#define KLEN1 2304        // 36*64, exact halves of K1
#define NBY   32          // T_TOK/128, both layers

typedef __attribute__((ext_vector_type(8))) short short8;
typedef __attribute__((ext_vector_type(4))) float floatx4;
typedef __attribute__((address_space(3))) void* lds_ptr_t;
typedef const __attribute__((address_space(1))) void* gmem_ptr_t;

__device__ __forceinline__ unsigned short f2bf(float f) {   // RNE (prep kernels)
  union { __hip_bfloat16 h; unsigned short u; } cv;
  cv.h = __float2bfloat16(f);
  return cv.u;
}
__device__ __forceinline__ float b2f(unsigned short u) {
  union { float f; unsigned u; } c; c.u = (unsigned)u << 16; return c.f;
}
__device__ __forceinline__ unsigned bfr(float f) {          // cheap near-RNE (expand hot path)
  union { float f; unsigned u; } c; c.f = f;
  return (c.u + 0x8000u) >> 16;
}
__device__ __forceinline__ float silu_f(float x) { return x / (1.0f + __expf(-x)); }

// All 8 cubic-basis slots for one group as 8 bf16 in a uint4 (branchless funnel shift).
__device__ __forceinline__ uint4 spline_pack(float h) {
  float u = (h + 2.2f) * 2.5f;
  int ji = (int)u;
  ji = ji < 0 ? 0 : (ji > 10 ? 10 : ji);
  float t = u - (float)ji;
  float it = 1.0f - t, t2 = t * t, t3 = t2 * t;
  float b0 = it * it * it * (1.0f / 6.0f);
  float b1 = (3.0f * t3 - 6.0f * t2 + 4.0f) * (1.0f / 6.0f);
  float b2 = (-3.0f * t3 + 3.0f * t2 + 3.0f * t + 1.0f) * (1.0f / 6.0f);
  float b3 = t3 * (1.0f / 6.0f);
  unsigned pk01 = bfr(b0) | (bfr(b1) << 16);
  unsigned pk23 = bfr(b2) | (bfr(b3) << 16);
  unsigned long long p64 = (unsigned long long)pk01 | ((unsigned long long)pk23 << 32);
  bool inR = (h >= -2.2f) && (h < 2.2f);
  p64 = inR ? p64 : 0ull;
  int sh = (ji - 3) * 16;
  int shr = sh < 0 ? -sh : 0;
  int shl = sh < 0 ? 0 : sh;
  __uint128_t v = ((__uint128_t)(p64 >> shr)) << shl;
  union { __uint128_t q; uint4 u4; } cv;
  cv.q = v;
  return cv.u4;
}

// W1'[o,k]: k<4096 -> spline_w1[o,k>>3,k&7]*scaler1[o,k>>3]; else base_w1. o < 2049.
__global__ void pack_w1_kernel(const float* __restrict__ bw, const float* __restrict__ sw,
                               const float* __restrict__ sc, unsigned short* __restrict__ W) {
  int k = blockIdx.x * 256 + threadIdx.x;  // grid exact: 18*256 = 4608
  int o = blockIdx.y;                      // < 2049
  float v;
  if (k < 4096) v = sw[(size_t)o * 4096 + k] * sc[(size_t)o * I1 + (k >> 3)];
  else          v = bw[(size_t)o * I1 + (k - 4096)];
  W[(size_t)o * K1 + k] = f2bf(v);
}

// W2'[o,k]: k<16392 -> spline_w2*scaler2; k<18441 -> base_w2; else 0
__global__ void pack_w2_kernel(const float* __restrict__ bw, const float* __restrict__ sw,
                               const float* __restrict__ sc, unsigned short* __restrict__ W) {
  int k = blockIdx.x * 256 + threadIdx.x;
  if (k >= K2) return;
  int o = blockIdx.y;                      // < 512
  float v = 0.0f;
  if (k < 16392)      v = sw[(size_t)o * 16392 + k] * sc[(size_t)o * I2 + (k >> 3)];
  else if (k < 18441) v = bw[(size_t)o * I2 + (k - 16392)];
  W[(size_t)o * K2 + k] = f2bf(v);
}

// A1[m, g*8..g*8+7]: g<512 -> spline basis of x[m,g]; g>=512 -> silu(x[m, (g-512)*8 + c]).
__global__ void expand1_kernel(const float* __restrict__ x, unsigned short* __restrict__ A) {
  int g = blockIdx.x * 256 + threadIdx.x;
  if (g >= NG1) return;
  int m = blockIdx.y;
  uint4 val;
  if (g < 512) {
    val = spline_pack(x[(size_t)m * I1 + g]);
  } else {
    const float4* xr = (const float4*)(x + (size_t)m * I1 + (size_t)(g - 512) * 8);
    float4 a = xr[0], b = xr[1];
    union { unsigned short s[8]; uint4 v; } pk;
    pk.s[0] = f2bf(silu_f(a.x)); pk.s[1] = f2bf(silu_f(a.y));
    pk.s[2] = f2bf(silu_f(a.z)); pk.s[3] = f2bf(silu_f(a.w));
    pk.s[4] = f2bf(silu_f(b.x)); pk.s[5] = f2bf(silu_f(b.y));
    pk.s[6] = f2bf(silu_f(b.z)); pk.s[7] = f2bf(silu_f(b.w));
    val = pk.v;
  }
  *(uint4*)(A + (size_t)m * K1 + (size_t)g * 8) = val;
}

// GEMV: H[:,2048] = A1 @ W1'[2048,:]^T. One wave per row m; 4608 = 9*64 groups of 8.
__global__ void gemv_col_kernel(const unsigned short* __restrict__ A1,
                                const unsigned short* __restrict__ W1,
                                float* __restrict__ Hcol) {
  int m = blockIdx.x * 4 + (threadIdx.x >> 6);
  int lane = threadIdx.x & 63;
  const unsigned short* a  = A1 + (size_t)m * K1;
  const unsigned short* wr = W1 + (size_t)2048 * K1;
  float s = 0.0f;
#pragma unroll
  for (int c = 0; c < 9; ++c) {
    int off = (c * 64 + lane) * 8;
    short8 av = *(const short8*)(a + off);
    short8 wv = *(const short8*)(wr + off);
#pragma unroll
    for (int j = 0; j < 8; ++j)
      s += b2f((unsigned short)av[j]) * b2f((unsigned short)wv[j]);
  }
#pragma unroll
  for (int d = 32; d >= 1; d >>= 1) s += __shfl_down(s, d);
  if (lane == 0) Hcol[m] = s;
}

// A2 from H = Ha + Hb (split-K partials, ldc N1G) with H[:,2048] in Hcol.
__global__ void expand2_kernel(const float* __restrict__ Ha, const float* __restrict__ Hb,
                               const float* __restrict__ Hcol, unsigned short* __restrict__ A) {
  int g = blockIdx.x * 256 + threadIdx.x;
  if (g >= NG2) return;
  int m = blockIdx.y;
  float hc = Hcol[m];
  uint4 val;
  if (g < 2049) {
    float h = (g < N1G) ? Ha[(size_t)m * N1G + g] + Hb[(size_t)m * N1G + g] : hc;
    val = spline_pack(h);
  } else if (g < 2306) {
    int c0 = (g - 2049) * 8;
    union { unsigned short s[8]; uint4 v; } pk;
#pragma unroll
    for (int c = 0; c < 8; ++c) {
      int idx = c0 + c;
      float v = 0.0f;
      if (idx < I2) {
        float h = (idx < N1G) ? Ha[(size_t)m * N1G + idx] + Hb[(size_t)m * N1G + idx] : hc;
        v = silu_f(h);
      }
      pk.s[c] = f2bf(v);
    }
    val = pk.v;
  } else {
    val = make_uint4(0u, 0u, 0u, 0u);
  }
  *(uint4*)(A + (size_t)m * K2 + (size_t)g * 8) = val;
}

// ---- Pure bf16 GEMM (round-1 proven structure, unchanged inner loop) ----
// C = A(MxK) * B(NxK)^T, row-major bf16, staged via global_load_lds w16 with XOR
// chunk pre-swizzle on the GLOBAL source address (linear LDS dest; read side
// applies the same XOR). 128x128 tile, 256 threads = 4 waves, 2-barrier K-loop.
// Multi-block residency (4 blocks/CU) provides the implicit stage/compute overlap
// (m114); rounds 2-3 proved 1-block/CU deep pipelines regress on this problem.
// storeMode 0: plain store into split-K partial C + bz*pslice (layer 1).
// storeMode 2: atomicAdd C[m*ldc+n] (layer 2 split-K).
__global__ __launch_bounds__(256, 4)
void gemm_bt_kernel(const unsigned short* __restrict__ Aw, const unsigned short* __restrict__ Bw,
                    float* __restrict__ C, int Ktot, int N, int ldc, int kLen,
                    int nBx, size_t pslice, int storeMode)
{
  __shared__ __align__(16) unsigned short As[128 * 64];
  __shared__ __align__(16) unsigned short Bs[128 * 64];

  // Grid decode: Lb = (p&7) + 8*(bx + nBx*(p>>3)), p = by + NBY*bz
  const int Lb = blockIdx.x;
  const int m8 = Lb & 7;
  const int r  = Lb >> 3;
  const int bx = r % nBx;
  const int p  = m8 + ((r / nBx) << 3);
  const int by = p & (NBY - 1);
  const int bz = p >> 5;                   // NBY = 32

  const int tid = threadIdx.x;
  const int ks = bz * kLen;
  int ke = ks + kLen; if (ke > Ktot) ke = Ktot;

  const int w = tid >> 6, L = tid & 63, q = L >> 4, ln = L & 15;
  const int wm = (w & 1) << 6, wn = (w >> 1) << 6;

  floatx4 zf = {0.f, 0.f, 0.f, 0.f};
  floatx4 acc[4][4];
#pragma unroll
  for (int mt = 0; mt < 4; ++mt)
#pragma unroll
    for (int nt = 0; nt < 4; ++nt)
      acc[mt][nt] = zf;

  // Staging: 4 chunks/thread/operand, lane-contiguous LDS dest (wave-uniform base + lane*16)
  const unsigned short* ga[4];
  const unsigned short* gb[4];
  int ldsOff[4];
#pragma unroll
  for (int r4 = 0; r4 < 4; ++r4) {
    int e = r4 * 256 + tid;
    int br = e >> 3;
    int cg = (e & 7) ^ (br & 7);
    ga[r4] = Aw + ((long)by * 128 + br) * (long)Ktot + ks + cg * 8;
    gb[r4] = Bw + ((long)bx * 128 + br) * (long)Ktot + ks + cg * 8;
    ldsOff[r4] = e * 8;
  }

  for (int kc = ks; kc < ke; kc += 64) {
    __syncthreads();                        // prior MFMA done reading LDS
#pragma unroll
    for (int r4 = 0; r4 < 4; ++r4) {
      __builtin_amdgcn_global_load_lds((gmem_ptr_t)ga[r4], (lds_ptr_t)&As[ldsOff[r4]], 16, 0, 0);
      ga[r4] += 64;
      __builtin_amdgcn_global_load_lds((gmem_ptr_t)gb[r4], (lds_ptr_t)&Bs[ldsOff[r4]], 16, 0, 0);
      gb[r4] += 64;
    }
    __syncthreads();                        // DMA drained (vmcnt(0) at barrier)

#pragma unroll
    for (int s = 0; s < 2; ++s) {
      short8 af[4], bf[4];
#pragma unroll
      for (int mt = 0; mt < 4; ++mt) {
        int rr = wm + mt * 16 + ln;
        int cl = ((s << 2) | q) ^ (rr & 7);
        af[mt] = *(const short8*)&As[rr * 64 + cl * 8];
      }
#pragma unroll
      for (int nt = 0; nt < 4; ++nt) {
        int rr = wn + nt * 16 + ln;
        int cl = ((s << 2) | q) ^ (rr & 7);
        bf[nt] = *(const short8*)&Bs[rr * 64 + cl * 8];
      }
#pragma unroll
      for (int mt = 0; mt < 4; ++mt)
#pragma unroll
        for (int nt = 0; nt < 4; ++nt)
          acc[mt][nt] = __builtin_amdgcn_mfma_f32_16x16x32_bf16(af[mt], bf[nt], acc[mt][nt], 0, 0, 0);
    }
  }

  // Epilogue. D layout: col = lane&15 (n), row = q*4+reg (m)  [m89-verified]
  if (storeMode == 0) {                     // plain store into split-K partial (layer 1)
    float* Cp = C + (size_t)bz * pslice;
#pragma unroll
    for (int mt = 0; mt < 4; ++mt) {
#pragma unroll
      for (int nt = 0; nt < 4; ++nt) {
        int n = bx * 128 + wn + nt * 16 + ln;
        if (n < N) {
          int m0 = by * 128 + wm + mt * 16 + q * 4;
#pragma unroll
          for (int rg = 0; rg < 4; ++rg)
            Cp[(size_t)(m0 + rg) * ldc + n] = acc[mt][nt][rg];
        }
      }
    }
  } else {                                  // atomic accumulate (layer 2, split-K)
#pragma unroll
    for (int mt = 0; mt < 4; ++mt) {
#pragma unroll
      for (int nt = 0; nt < 4; ++nt) {
        int n = bx * 128 + wn + nt * 16 + ln;
        if (n < N) {
          int m0 = by * 128 + wm + mt * 16 + q * 4;
#pragma unroll
          for (int rg = 0; rg < 4; ++rg)
            atomicAdd(&C[(size_t)(m0 + rg) * ldc + n], acc[mt][nt][rg]);
        }
      }
    }
  }
}

extern "C" void kernel_launch(void* const* d_in, const int* in_sizes, int n_in,
                              void* d_out, int out_size, void* d_ws, size_t ws_size,
                              hipStream_t stream) {
  const float* x   = (const float*)d_in[0];
  const float* bw1 = (const float*)d_in[1];
  const float* sw1 = (const float*)d_in[2];
  const float* sc1 = (const float*)d_in[3];
  const float* bw2 = (const float*)d_in[4];
  const float* sw2 = (const float*)d_in[5];
  const float* sc2 = (const float*)d_in[6];
  float* out = (float*)d_out;

  // Workspace: Ha(33.6) | Hb(33.6) | Hcol(64KB) | W2(19.0) | A2(152.0; A1 37.7 + W1 18.9 aliased)
  // Total ~238 MB. A1/W1 die after gemm1+gemv; expand2 overwrites (stream-ordered).
  float* Ha = (float*)d_ws;
  float* Hb = Ha + HPART;
  float* Hcol = Hb + HPART;
  unsigned short* W2 = (unsigned short*)(Hcol + 16384);
  unsigned short* A2 = W2 + (size_t)O2 * K2;
  unsigned short* A1 = A2;                              // alias (first 37.7 MB)
  unsigned short* W1 = A1 + (size_t)T_TOK * K1;         // next 18.9 MB

  hipMemsetAsync(d_out, 0, (size_t)out_size * sizeof(float), stream);

  pack_w1_kernel<<<dim3(K1 / 256, O1), 256, 0, stream>>>(bw1, sw1, sc1, W1);
  pack_w2_kernel<<<dim3((K2 + 255) / 256, O2), 256, 0, stream>>>(bw2, sw2, sc2, W2);
  expand1_kernel<<<dim3((NG1 + 255) / 256, T_TOK), 256, 0, stream>>>(x, A1);

  // H column 2048 via GEMV (keeps gemm1 at N=2048 exactly)
  gemv_col_kernel<<<T_TOK / 4, 256, 0, stream>>>(A1, W1, Hcol);

  // Layer 1: Ha/Hb = A1 @ W1'^T. M=4096, N=2048, K=4608.
  // 16 bx x 32 by x split-K 2 = 1024 blocks = exactly 4 blocks/CU (balanced).
  gemm_bt_kernel<<<16 * NBY * 2, 256, 0, stream>>>(
      A1, W1, Ha, K1, N1G, N1G, KLEN1, 16, HPART, 0);

  expand2_kernel<<<dim3((NG2 + 255) / 256, T_TOK), 256, 0, stream>>>(Ha, Hb, Hcol, A2);

  // Layer 2: out += A2 @ W2'^T. M=4096, N=512, K=18560; 4 bx x 32 by x split-K 8 = 1024 blocks.
  gemm_bt_kernel<<<(O2 / 128) * NBY * SPLITS2, 256, 0, stream>>>(
      A2, W2, out, K2, O2, O2, KLEN2, 4, 0, 2);
}